// Round 2
// baseline (863.084 us; speedup 1.0000x reference)
//
#include <hip/hip_runtime.h>
#include <hip/hip_bf16.h>

typedef _Float16 f16x8 __attribute__((ext_vector_type(8)));
typedef float    f32x4 __attribute__((ext_vector_type(4)));

#define T_STEPS 1024
#define BATCH   128
#define DH      256   // hidden == input dim == 256

// ---------------------------------------------------------------------------
// Kernel 1: xp[t,b,:] = x[t,b,:] @ W_ih^T + b_ih + b_hh   (written into d_out)
// f16 hi/lo split (3 MFMA passes) => ~fp32 accuracy at f16-MFMA rate.
// ---------------------------------------------------------------------------
#define BM 128
#define BN 128
#define BK 64

__device__ __forceinline__ void stage_tile(const float* __restrict__ src,
                                           int row0, int kc,
                                           unsigned short* hi, unsigned short* lo,
                                           int t) {
#pragma unroll
  for (int i = 0; i < 8; ++i) {
    int f   = i * 256 + t;      // float4 slot 0..2047
    int row = f >> 4;           // 16 float4 per row
    int q   = f & 15;
    const float4 v = *(const float4*)&src[(size_t)(row0 + row) * 256 + kc + q * 4];
    _Float16 h0 = (_Float16)v.x, h1 = (_Float16)v.y,
             h2 = (_Float16)v.z, h3 = (_Float16)v.w;
    _Float16 l0 = (_Float16)(v.x - (float)h0), l1 = (_Float16)(v.y - (float)h1),
             l2 = (_Float16)(v.z - (float)h2), l3 = (_Float16)(v.w - (float)h3);
    unsigned int off = (unsigned int)(row * 128 + q * 8) ^ ((row & 7) << 4);
    union { _Float16 h[4]; uint2 u; } ph, pl;
    ph.h[0] = h0; ph.h[1] = h1; ph.h[2] = h2; ph.h[3] = h3;
    pl.h[0] = l0; pl.h[1] = l1; pl.h[2] = l2; pl.h[3] = l3;
    *(uint2*)((char*)hi + off) = ph.u;
    *(uint2*)((char*)lo + off) = pl.u;
  }
}

__global__ __launch_bounds__(256, 2) void xp_gemm(
    const float* __restrict__ x,   const float* __restrict__ Wih,
    const float* __restrict__ bih, const float* __restrict__ bhh,
    float* __restrict__ out) {
  __shared__ __align__(16) unsigned short Ah[BM * BK], Al[BM * BK];
  __shared__ __align__(16) unsigned short Bh[BN * BK], Bl[BN * BK];
  const int t    = threadIdx.x;
  const int m0   = blockIdx.x * BM;
  const int n0   = blockIdx.y * BN;
  const int lane = t & 63;
  const int wave = t >> 6;
  const int wm = wave >> 1, wn = wave & 1;

  f32x4 acc[4][4];
#pragma unroll
  for (int i = 0; i < 4; ++i)
#pragma unroll
    for (int j = 0; j < 4; ++j) acc[i][j] = (f32x4)0.0f;

  for (int kc = 0; kc < 256; kc += BK) {
    stage_tile(x,   m0, kc, Ah, Al, t);
    stage_tile(Wih, n0, kc, Bh, Bl, t);
    __syncthreads();
#pragma unroll
    for (int ks = 0; ks < 2; ++ks) {
      f16x8 ah[4], al[4], bh[4], bl[4];
#pragma unroll
      for (int mi = 0; mi < 4; ++mi) {
        int row = wm * 64 + mi * 16 + (lane & 15);
        unsigned int off =
            (unsigned int)(row * 128 + ks * 64 + ((lane >> 4) << 4)) ^ ((row & 7) << 4);
        ah[mi] = *(const f16x8*)((const char*)Ah + off);
        al[mi] = *(const f16x8*)((const char*)Al + off);
      }
#pragma unroll
      for (int ni = 0; ni < 4; ++ni) {
        int row = wn * 64 + ni * 16 + (lane & 15);
        unsigned int off =
            (unsigned int)(row * 128 + ks * 64 + ((lane >> 4) << 4)) ^ ((row & 7) << 4);
        bh[ni] = *(const f16x8*)((const char*)Bh + off);
        bl[ni] = *(const f16x8*)((const char*)Bl + off);
      }
#pragma unroll
      for (int mi = 0; mi < 4; ++mi)
#pragma unroll
        for (int ni = 0; ni < 4; ++ni) {
          acc[mi][ni] = __builtin_amdgcn_mfma_f32_16x16x32_f16(ah[mi], bh[ni], acc[mi][ni], 0, 0, 0);
          acc[mi][ni] = __builtin_amdgcn_mfma_f32_16x16x32_f16(ah[mi], bl[ni], acc[mi][ni], 0, 0, 0);
          acc[mi][ni] = __builtin_amdgcn_mfma_f32_16x16x32_f16(al[mi], bh[ni], acc[mi][ni], 0, 0, 0);
        }
    }
    __syncthreads();
  }
#pragma unroll
  for (int ni = 0; ni < 4; ++ni) {
    int col = n0 + wn * 64 + ni * 16 + (lane & 15);
    float bias = bih[col] + bhh[col];
#pragma unroll
    for (int mi = 0; mi < 4; ++mi) {
      int rbase = m0 + wm * 64 + mi * 16 + ((lane >> 4) << 2);
#pragma unroll
      for (int r = 0; r < 4; ++r)
        out[(size_t)(rbase + r) * DH + col] = acc[mi][ni][r] + bias;
    }
  }
}

// ---------------------------------------------------------------------------
// Kernel 2: recurrence. 1 WG per batch element, 1024 threads (16 waves).
// Thread (wave wv, lane): jl = lane>>3 (8 output pairs), kg = lane&7 (k-split 8).
// Owns outputs j0 = wv*16 + jl*2 (+0,+1), k-slice kg*32..+31 -> 64 W floats in
// VGPRs (static indexing). Per step: 8x b128 broadcast h-reads (k-order
// xor-rotated by kg so the 8 wave-addresses cover all 32 banks), 64 FMA,
// 3-stage shfl_xor reduce (intra-wave, no LDS), fast tanh, kg<2 lanes write.
// hs double-buffered + compile-time phase unroll => ONE barrier per step.
// xp read from d_out, overwritten in place by h (same lane loads & stores a
// given address => program-order safe).
// ---------------------------------------------------------------------------
__device__ __forceinline__ float tanh_fast(float x) {
  float xc = fminf(9.0f, fmaxf(-9.0f, x));                 // tanh(9) == 1.0f - 3e-8
  float e2 = __builtin_amdgcn_exp2f(2.885390082f * xc);    // e^(2x) = 2^(2*log2e*x)
  return 1.0f - 2.0f * __builtin_amdgcn_rcpf(e2 + 1.0f);   // (e^2x-1)/(e^2x+1)
}

__global__ __launch_bounds__(1024) void rnn_rec(
    const float* __restrict__ Whh, float* __restrict__ xh) {
  const int b    = blockIdx.x;
  const int t    = threadIdx.x;
  const int lane = t & 63;
  const int wv   = t >> 6;
  const int jl   = lane >> 3;      // 0..7
  const int kg   = lane & 7;       // 0..7
  const int j0   = wv * 16 + jl * 2;

  __shared__ float hs[2][DH];

  // W_hh slice -> 64 VGPRs. k order xor-rotated: w*[qq*4+e] holds k = kg*32 + (qq^kg)*4 + e
  float w0[32], w1[32];
#pragma unroll
  for (int qq = 0; qq < 8; ++qq) {
    int kbase = kg * 32 + ((qq ^ kg) << 2);
    *(float4*)&w0[qq * 4] = *(const float4*)&Whh[(size_t)(j0    ) * DH + kbase];
    *(float4*)&w1[qq * 4] = *(const float4*)&Whh[(size_t)(j0 + 1) * DH + kbase];
  }

  // precomputed LDS byte offsets for the 8 h-quads (loop-invariant)
  unsigned hoff[8];
#pragma unroll
  for (int qq = 0; qq < 8; ++qq)
    hoff[qq] = (unsigned)(kg * 128 + ((qq ^ kg) << 4));

  if (t < DH) { hs[0][t] = 0.0f; }

  // in-place xp/h pointer for this thread's column (valid for kg<2)
  float* pxp = xh + (size_t)b * DH + j0 + (kg & 1);
  const bool writer = (kg < 2);

  float xpc = 0.0f;
  if (writer) xpc = pxp[0];        // xp row 0
  __syncthreads();

#define STEP(S, P)                                                             \
  {                                                                            \
    const int sn = (S) + 1;                                                    \
    float xpn = 0.0f;                                                          \
    if (sn < T_STEPS && writer) xpn = pxp[(size_t)sn * (BATCH * DH)];          \
    float a0 = 0.0f, a1 = 0.0f;                                                \
    const char* hb = (const char*)&hs[P][0];                                   \
    _Pragma("unroll")                                                          \
    for (int qq = 0; qq < 8; ++qq) {                                           \
      float4 hv = *(const float4*)(hb + hoff[qq]);                             \
      a0 = fmaf(w0[qq*4+0], hv.x, a0); a0 = fmaf(w0[qq*4+1], hv.y, a0);        \
      a0 = fmaf(w0[qq*4+2], hv.z, a0); a0 = fmaf(w0[qq*4+3], hv.w, a0);        \
      a1 = fmaf(w1[qq*4+0], hv.x, a1); a1 = fmaf(w1[qq*4+1], hv.y, a1);        \
      a1 = fmaf(w1[qq*4+2], hv.z, a1); a1 = fmaf(w1[qq*4+3], hv.w, a1);        \
    }                                                                          \
    _Pragma("unroll")                                                          \
    for (int m = 1; m < 8; m <<= 1) {                                          \
      a0 += __shfl_xor(a0, m, 64);                                             \
      a1 += __shfl_xor(a1, m, 64);                                             \
    }                                                                          \
    float v = ((kg & 1) ? a1 : a0) + xpc;                                      \
    float h = tanh_fast(v);                                                    \
    if (writer) {                                                              \
      hs[P ^ 1][j0 + kg] = h;                                                  \
      pxp[(size_t)(S) * (BATCH * DH)] = h;                                     \
    }                                                                          \
    xpc = xpn;                                                                 \
    __syncthreads();                                                           \
  }

  for (int s = 0; s < T_STEPS; s += 2) {
    STEP(s, 0)
    STEP(s + 1, 1)
  }
#undef STEP
}

extern "C" void kernel_launch(void* const* d_in, const int* in_sizes, int n_in,
                              void* d_out, int out_size, void* d_ws, size_t ws_size,
                              hipStream_t stream) {
  const float* x   = (const float*)d_in[0];
  const float* Wih = (const float*)d_in[1];
  const float* Whh = (const float*)d_in[2];
  const float* bih = (const float*)d_in[3];
  const float* bhh = (const float*)d_in[4];
  float* out = (float*)d_out;

  dim3 g1((T_STEPS * BATCH) / BM, DH / BN);   // 1024 x 2
  xp_gemm<<<g1, dim3(256), 0, stream>>>(x, Wih, bih, bhh, out);
  rnn_rec<<<BATCH, dim3(1024), 0, stream>>>(Whh, out);
}